// Round 1
// baseline (405.150 us; speedup 1.0000x reference)
//
#include <hip/hip_runtime.h>
#include <hip/hip_bf16.h>

#define B_ 16
#define S_ 1024
#define D_ 512
#define H_ 8
#define DH_ 64

typedef __attribute__((ext_vector_type(8))) short bf16x8;
typedef __attribute__((ext_vector_type(4))) float f32x4;

__device__ __forceinline__ short f2bf(float f) {
    __hip_bfloat16 h = __float2bfloat16(f);
    return *reinterpret_cast<short*>(&h);
}

// ---------------------------------------------------------------------------
// K1: conv1d(stride=pool) + bias + pos-emb + exact GELU + LayerNorm over D
//     -> n1 bf16, layout (B*S, 512) row-major
// ---------------------------------------------------------------------------
__global__ __launch_bounds__(256) void k1_conv_gelu_ln(
    const float* __restrict__ ts, const float* __restrict__ conv_w,
    const float* __restrict__ conv_b, const float* __restrict__ pe,
    const float* __restrict__ g1, const float* __restrict__ b1,
    __hip_bfloat16* __restrict__ n1)
{
    const int row = blockIdx.x;          // b*S + s
    const int b = row >> 10, s = row & 1023;
    const int t = threadIdx.x;
    const float4 x = *reinterpret_cast<const float4*>(ts + b * 4096 + s * 4);

    float a[2];
#pragma unroll
    for (int k = 0; k < 2; ++k) {
        const int d = t + k * 256;
        const float4 w = *reinterpret_cast<const float4*>(conv_w + d * 4);
        float v = x.x * w.x + x.y * w.y + x.z * w.z + x.w * w.w
                + conv_b[d] + pe[s * 512 + d];
        a[k] = 0.5f * v * (1.0f + erff(v * 0.70710678118654752f));
    }
    float sum = a[0] + a[1], sq = a[0] * a[0] + a[1] * a[1];
#pragma unroll
    for (int off = 32; off > 0; off >>= 1) {
        sum += __shfl_down(sum, off);
        sq  += __shfl_down(sq, off);
    }
    __shared__ float rs[4], rq[4];
    const int wv = t >> 6, ln = t & 63;
    if (ln == 0) { rs[wv] = sum; rq[wv] = sq; }
    __syncthreads();
    sum = rs[0] + rs[1] + rs[2] + rs[3];
    sq  = rq[0] + rq[1] + rq[2] + rq[3];
    const float mean = sum * (1.0f / 512.0f);
    const float var  = (sq - 512.0f * mean * mean) * (1.0f / 511.0f);
    const float rstd = rsqrtf(var + 1e-5f);
    const float gg = g1[s], bb = b1[s];
#pragma unroll
    for (int k = 0; k < 2; ++k) {
        const int d = t + k * 256;
        n1[(size_t)row * 512 + d] = __float2bfloat16(gg * ((a[k] - mean) * rstd) + bb);
    }
}

// ---------------------------------------------------------------------------
// GEMM: out[r][n] = sum_d A[r][d] * W[n][d]   (A bf16 16384x512, W f32 512x512)
// BM=128 BN=64 BK=64, 4 waves (2x2), each wave 64x32 = 4x2 16x16 frags.
// MODE 0: += ts_emb[te[b]][n], write bf16 row-major
// MODE 1: write bf16 to (B,H,S,DH)     (Q or K)
// MODE 2: write bf16 to (B,H,DH,S)     (V transposed)
// MODE 3: += bo[n], write f32 row-major
// ---------------------------------------------------------------------------
template<int MODE>
__global__ __launch_bounds__(256) void gemm_k(
    const __hip_bfloat16* __restrict__ A,
    const float* __restrict__ W,
    void* __restrict__ outp,
    const float* __restrict__ aux,
    const int* __restrict__ te)
{
    __shared__ char lA[128 * 128];   // 128 rows x 64 bf16 (128B/row), swizzled
    __shared__ char lB[64 * 128];    // 64 rows x 64 bf16, swizzled

    const int t = threadIdx.x;
    const int lane = t & 63;
    const int wv = t >> 6;
    const int wm = wv & 1, wn = wv >> 1;
    const int Rb = blockIdx.x * 128;
    const int Nb = blockIdx.y * 64;
    const int g = lane >> 4, lr = lane & 15;

    const f32x4 zero = {0.f, 0.f, 0.f, 0.f};
    f32x4 acc[4][2];
#pragma unroll
    for (int i = 0; i < 4; ++i)
#pragma unroll
        for (int j = 0; j < 2; ++j) acc[i][j] = zero;

    for (int kt = 0; kt < 8; ++kt) {
        const int k0 = kt * 64;
        // stage A tile: 128x64 bf16
#pragma unroll
        for (int p = 0; p < 4; ++p) {
            const int idx = p * 256 + t;
            const int row = idx >> 3, ch = idx & 7;
            bf16x8 v = *reinterpret_cast<const bf16x8*>(
                A + (size_t)(Rb + row) * 512 + k0 + ch * 8);
            *reinterpret_cast<bf16x8*>(lA + row * 128 + ((ch ^ (row & 7)) << 4)) = v;
        }
        // stage W tile: 64x64 f32 -> bf16
        {
            const int row = t >> 2, seg = t & 3;
            const float4* wp = reinterpret_cast<const float4*>(
                W + (size_t)(Nb + row) * 512 + k0 + seg * 16);
            alignas(16) short tmp[16];
#pragma unroll
            for (int i = 0; i < 4; ++i) {
                const float4 f = wp[i];
                tmp[i * 4 + 0] = f2bf(f.x);
                tmp[i * 4 + 1] = f2bf(f.y);
                tmp[i * 4 + 2] = f2bf(f.z);
                tmp[i * 4 + 3] = f2bf(f.w);
            }
            const int c0 = seg * 2;
            *reinterpret_cast<bf16x8*>(lB + row * 128 + (((c0) ^ (row & 7)) << 4)) =
                *reinterpret_cast<bf16x8*>(tmp);
            *reinterpret_cast<bf16x8*>(lB + row * 128 + (((c0 + 1) ^ (row & 7)) << 4)) =
                *reinterpret_cast<bf16x8*>(tmp + 8);
        }
        __syncthreads();
#pragma unroll
        for (int kk = 0; kk < 2; ++kk) {
            bf16x8 af[4], bfv[2];
            const int ch = kk * 4 + g;
#pragma unroll
            for (int mt = 0; mt < 4; ++mt) {
                const int row = wm * 64 + mt * 16 + lr;
                af[mt] = *reinterpret_cast<const bf16x8*>(
                    lA + row * 128 + ((ch ^ (row & 7)) << 4));
            }
#pragma unroll
            for (int nt = 0; nt < 2; ++nt) {
                const int row = wn * 32 + nt * 16 + lr;
                bfv[nt] = *reinterpret_cast<const bf16x8*>(
                    lB + row * 128 + ((ch ^ (row & 7)) << 4));
            }
#pragma unroll
            for (int mt = 0; mt < 4; ++mt)
#pragma unroll
                for (int nt = 0; nt < 2; ++nt)
                    acc[mt][nt] = __builtin_amdgcn_mfma_f32_16x16x32_bf16(
                        af[mt], bfv[nt], acc[mt][nt], 0, 0, 0);
        }
        __syncthreads();
    }

    // epilogue
#pragma unroll
    for (int mt = 0; mt < 4; ++mt) {
#pragma unroll
        for (int nt = 0; nt < 2; ++nt) {
#pragma unroll
            for (int r = 0; r < 4; ++r) {
                const int R = Rb + wm * 64 + mt * 16 + 4 * g + r;
                const int N = Nb + wn * 32 + nt * 16 + lr;
                float v = acc[mt][nt][r];
                if (MODE == 0) {
                    const int b = R >> 10;
                    v += aux[(size_t)te[b] * 512 + N];
                    reinterpret_cast<__hip_bfloat16*>(outp)[(size_t)R * 512 + N] =
                        __float2bfloat16(v);
                } else if (MODE == 1) {
                    const int b = R >> 10, s = R & 1023, h = N >> 6, c = N & 63;
                    reinterpret_cast<__hip_bfloat16*>(outp)
                        [(((size_t)(b * 8 + h)) * 1024 + s) * 64 + c] = __float2bfloat16(v);
                } else if (MODE == 2) {
                    const int b = R >> 10, s = R & 1023, h = N >> 6, c = N & 63;
                    reinterpret_cast<__hip_bfloat16*>(outp)
                        [(((size_t)(b * 8 + h)) * 64 + c) * 1024 + s] = __float2bfloat16(v);
                } else {
                    reinterpret_cast<float*>(outp)[(size_t)R * 512 + N] = v + aux[N];
                }
            }
        }
    }
}

// ---------------------------------------------------------------------------
// Flash attention (swapped roles): out[j] = sum_{i<=j} softmax_i(Q_i.K_j) V_i
// flashQ = K-matrix rows, flashK = Q-matrix rows, V pre-transposed (B,H,DH,S).
// Block: 4 waves x 16 j-rows. One (b,h) per blockIdx.y, 64 j per blockIdx.x.
// ---------------------------------------------------------------------------
__global__ __launch_bounds__(256) void attn_k(
    const __hip_bfloat16* __restrict__ Qm,   // (B,H,S,64)
    const __hip_bfloat16* __restrict__ Km,   // (B,H,S,64)
    const __hip_bfloat16* __restrict__ Vt,   // (B,H,64,S)
    __hip_bfloat16* __restrict__ cat)        // (B,S,512)
{
    __shared__ short Plds[4][16 * 32];
    const int t = threadIdx.x, lane = t & 63, w = t >> 6;
    const int g = lane >> 4, lr = lane & 15;
    const int jb = blockIdx.x, bh = blockIdx.y;
    const int b = bh >> 3, h = bh & 7;
    const int j0 = jb * 64 + w * 16;

    const __hip_bfloat16* Qh = Qm + (size_t)bh * S_ * 64;
    const __hip_bfloat16* Kh = Km + (size_t)bh * S_ * 64;
    const __hip_bfloat16* Vh = Vt + (size_t)bh * 64 * S_;

    // flash-Q fragments (rows j0..j0+15 of K-matrix), K=64 split in two
    bf16x8 aq0 = *reinterpret_cast<const bf16x8*>(Kh + (size_t)(j0 + lr) * 64 + 8 * g);
    bf16x8 aq1 = *reinterpret_cast<const bf16x8*>(Kh + (size_t)(j0 + lr) * 64 + 32 + 8 * g);

    const f32x4 zero = {0.f, 0.f, 0.f, 0.f};
    f32x4 o[4];
#pragma unroll
    for (int i = 0; i < 4; ++i) o[i] = zero;
    float m[4]    = {-3e38f, -3e38f, -3e38f, -3e38f};
    float lsum[4] = {0.f, 0.f, 0.f, 0.f};

    short* P = Plds[w];

    for (int i0 = 0; i0 <= j0 + 15; i0 += 32) {
        f32x4 sc[2];
#pragma unroll
        for (int it = 0; it < 2; ++it) {
            sc[it] = zero;
            const int ib = i0 + it * 16;
            bf16x8 b0 = *reinterpret_cast<const bf16x8*>(Qh + (size_t)(ib + lr) * 64 + 8 * g);
            bf16x8 b1 = *reinterpret_cast<const bf16x8*>(Qh + (size_t)(ib + lr) * 64 + 32 + 8 * g);
            sc[it] = __builtin_amdgcn_mfma_f32_16x16x32_bf16(aq0, b0, sc[it], 0, 0, 0);
            sc[it] = __builtin_amdgcn_mfma_f32_16x16x32_bf16(aq1, b1, sc[it], 0, 0, 0);
        }
        const bool diag = (i0 + 31 > j0);
#pragma unroll
        for (int it = 0; it < 2; ++it) {
#pragma unroll
            for (int r = 0; r < 4; ++r) {
                float v = sc[it][r] * 0.125f;
                if (diag) {
                    const int i_ = i0 + it * 16 + lr;
                    const int j_ = j0 + 4 * g + r;
                    if (i_ > j_) v = -3e38f;
                }
                sc[it][r] = v;
            }
        }
        // online softmax per row r (row stats shared across the 16 lanes of a group)
#pragma unroll
        for (int r = 0; r < 4; ++r) {
            float v = fmaxf(sc[0][r], sc[1][r]);
#pragma unroll
            for (int off = 1; off < 16; off <<= 1) v = fmaxf(v, __shfl_xor(v, off));
            const float mn = fmaxf(m[r], v);
            const float alpha = __expf(m[r] - mn);
            const float p0 = __expf(sc[0][r] - mn);
            const float p1 = __expf(sc[1][r] - mn);
            float ps = p0 + p1;
#pragma unroll
            for (int off = 1; off < 16; off <<= 1) ps += __shfl_xor(ps, off);
            lsum[r] = lsum[r] * alpha + ps;
            m[r] = mn;
            o[0][r] *= alpha; o[1][r] *= alpha; o[2][r] *= alpha; o[3][r] *= alpha;
            // write P tile (16x32 bf16, 16B-chunk swizzled) for PV A-operand
            const int row = 4 * g + r;
            const int ch0 = (lr >> 3);         // it=0: cols 0..15
            const int ch1 = 2 + (lr >> 3);     // it=1: cols 16..31
            P[row * 32 + ((ch0 ^ (row & 3)) << 3) + (lr & 7)] = f2bf(p0);
            P[row * 32 + ((ch1 ^ (row & 3)) << 3) + (lr & 7)] = f2bf(p1);
        }
        // PV: P(16x32) x V(32x64)
        bf16x8 ap = *reinterpret_cast<const bf16x8*>(&P[lr * 32 + ((g ^ (lr & 3)) << 3)]);
#pragma unroll
        for (int ct = 0; ct < 4; ++ct) {
            bf16x8 bv = *reinterpret_cast<const bf16x8*>(
                Vh + (size_t)(ct * 16 + lr) * 1024 + i0 + 8 * g);
            o[ct] = __builtin_amdgcn_mfma_f32_16x16x32_bf16(ap, bv, o[ct], 0, 0, 0);
        }
    }

#pragma unroll
    for (int ct = 0; ct < 4; ++ct) {
#pragma unroll
        for (int r = 0; r < 4; ++r) {
            const int j = j0 + 4 * g + r;
            const float v = o[ct][r] / lsum[r];
            cat[((size_t)(b * 1024 + j)) * 512 + h * 64 + ct * 16 + lr] =
                __float2bfloat16(v);
        }
    }
}

// ---------------------------------------------------------------------------
// K5: residual (recompute conv) + LayerNorm over D, write (B,D,S) f32
// ---------------------------------------------------------------------------
__global__ __launch_bounds__(256) void k5_res_ln(
    const float* __restrict__ outf,  // (B*S,512) = Wo@cat + bo
    const float* __restrict__ ts, const float* __restrict__ conv_w,
    const float* __restrict__ conv_b, const float* __restrict__ pe,
    const float* __restrict__ g2, const float* __restrict__ b2,
    float* __restrict__ out)         // (B,512,1024)
{
    const int row = blockIdx.x;
    const int b = row >> 10, s = row & 1023;
    const int t = threadIdx.x;
    const float4 x = *reinterpret_cast<const float4*>(ts + b * 4096 + s * 4);

    float a[2];
#pragma unroll
    for (int k = 0; k < 2; ++k) {
        const int d = t + k * 256;
        const float4 w = *reinterpret_cast<const float4*>(conv_w + d * 4);
        const float conv = x.x * w.x + x.y * w.y + x.z * w.z + x.w * w.w
                         + conv_b[d] + pe[s * 512 + d];
        a[k] = outf[(size_t)row * 512 + d] + conv;
    }
    float sum = a[0] + a[1], sq = a[0] * a[0] + a[1] * a[1];
#pragma unroll
    for (int off = 32; off > 0; off >>= 1) {
        sum += __shfl_down(sum, off);
        sq  += __shfl_down(sq, off);
    }
    __shared__ float rs[4], rq[4];
    const int wv = t >> 6, ln = t & 63;
    if (ln == 0) { rs[wv] = sum; rq[wv] = sq; }
    __syncthreads();
    sum = rs[0] + rs[1] + rs[2] + rs[3];
    sq  = rq[0] + rq[1] + rq[2] + rq[3];
    const float mean = sum * (1.0f / 512.0f);
    const float var  = (sq - 512.0f * mean * mean) * (1.0f / 511.0f);
    const float rstd = rsqrtf(var + 1e-5f);
    const float gg = g2[s], bb = b2[s];
#pragma unroll
    for (int k = 0; k < 2; ++k) {
        const int d = t + k * 256;
        out[((size_t)b * 512 + d) * 1024 + s] = gg * ((a[k] - mean) * rstd) + bb;
    }
}

// ---------------------------------------------------------------------------
extern "C" void kernel_launch(void* const* d_in, const int* in_sizes, int n_in,
                              void* d_out, int out_size, void* d_ws, size_t ws_size,
                              hipStream_t stream)
{
    const float* ts     = (const float*)d_in[0];
    const int*   te     = (const int*)d_in[1];
    const float* conv_w = (const float*)d_in[2];
    const float* conv_b = (const float*)d_in[3];
    const float* pe     = (const float*)d_in[4];
    const float* ts_emb = (const float*)d_in[5];
    const float* g1     = (const float*)d_in[6];
    const float* b1     = (const float*)d_in[7];
    const float* M      = (const float*)d_in[8];
    const float* Wq     = (const float*)d_in[9];
    const float* Wk     = (const float*)d_in[10];
    const float* Wv     = (const float*)d_in[11];
    const float* Wo     = (const float*)d_in[12];
    const float* bo     = (const float*)d_in[13];
    const float* g2     = (const float*)d_in[14];
    const float* b2     = (const float*)d_in[15];

    char* ws = (char*)d_ws;
    __hip_bfloat16* n1    = (__hip_bfloat16*)(ws);                      // 16MB
    __hip_bfloat16* dense = (__hip_bfloat16*)(ws + (16ull << 20));      // 16MB
    __hip_bfloat16* q     = (__hip_bfloat16*)(ws + (32ull << 20));      // 16MB
    __hip_bfloat16* k     = (__hip_bfloat16*)(ws + (48ull << 20));      // 16MB
    __hip_bfloat16* vT    = (__hip_bfloat16*)(ws + (64ull << 20));      // 16MB
    __hip_bfloat16* cat   = (__hip_bfloat16*)(ws + (80ull << 20));      // 16MB
    float* outf           = (float*)(ws);  // reuse n1+dense region (32MB), both dead

    k1_conv_gelu_ln<<<16384, 256, 0, stream>>>(ts, conv_w, conv_b, pe, g1, b1, n1);
    gemm_k<0><<<dim3(128, 8), 256, 0, stream>>>(n1, M, dense, ts_emb, te);
    gemm_k<1><<<dim3(128, 8), 256, 0, stream>>>(dense, Wq, q, nullptr, nullptr);
    gemm_k<1><<<dim3(128, 8), 256, 0, stream>>>(dense, Wk, k, nullptr, nullptr);
    gemm_k<2><<<dim3(128, 8), 256, 0, stream>>>(dense, Wv, vT, nullptr, nullptr);
    attn_k<<<dim3(16, 128), 256, 0, stream>>>(q, k, vT, cat);
    gemm_k<3><<<dim3(128, 8), 256, 0, stream>>>(cat, Wo, outf, bo, nullptr);
    k5_res_ln<<<16384, 256, 0, stream>>>(outf, ts, conv_w, conv_b, pe, g2, b2,
                                         (float*)d_out);
}

// Round 3
// 348.603 us; speedup vs baseline: 1.1622x; 1.1622x over previous
//
#include <hip/hip_runtime.h>
#include <hip/hip_bf16.h>

#define B_ 16
#define S_ 1024
#define D_ 512
#define H_ 8
#define DH_ 64

typedef __attribute__((ext_vector_type(8))) short bf16x8;
typedef __attribute__((ext_vector_type(4))) short bf16x4;
typedef __attribute__((ext_vector_type(4))) float f32x4;
typedef __attribute__((ext_vector_type(16))) float f32x16;

__device__ __forceinline__ short f2bf(float f) {
    __hip_bfloat16 h = __float2bfloat16(f);
    return *reinterpret_cast<short*>(&h);
}
__device__ __forceinline__ unsigned pack_bf2(float lo, float hi) {
    unsigned a = (unsigned)(unsigned short)f2bf(lo);
    unsigned b = (unsigned)(unsigned short)f2bf(hi);
    return a | (b << 16);
}

// ---------------------------------------------------------------------------
// K1: conv1d(stride=pool) + bias + pos-emb + exact GELU + LayerNorm over D
//     -> n1 bf16, layout (B*S, 512) row-major
// ---------------------------------------------------------------------------
__global__ __launch_bounds__(256) void k1_conv_gelu_ln(
    const float* __restrict__ ts, const float* __restrict__ conv_w,
    const float* __restrict__ conv_b, const float* __restrict__ pe,
    const float* __restrict__ g1, const float* __restrict__ b1,
    __hip_bfloat16* __restrict__ n1)
{
    const int row = blockIdx.x;          // b*S + s
    const int b = row >> 10, s = row & 1023;
    const int t = threadIdx.x;
    const float4 x = *reinterpret_cast<const float4*>(ts + b * 4096 + s * 4);

    float a[2];
#pragma unroll
    for (int k = 0; k < 2; ++k) {
        const int d = t + k * 256;
        const float4 w = *reinterpret_cast<const float4*>(conv_w + d * 4);
        float v = x.x * w.x + x.y * w.y + x.z * w.z + x.w * w.w
                + conv_b[d] + pe[s * 512 + d];
        a[k] = 0.5f * v * (1.0f + erff(v * 0.70710678118654752f));
    }
    float sum = a[0] + a[1], sq = a[0] * a[0] + a[1] * a[1];
#pragma unroll
    for (int off = 32; off > 0; off >>= 1) {
        sum += __shfl_down(sum, off);
        sq  += __shfl_down(sq, off);
    }
    __shared__ float rs[4], rq[4];
    const int wv = t >> 6, ln = t & 63;
    if (ln == 0) { rs[wv] = sum; rq[wv] = sq; }
    __syncthreads();
    sum = rs[0] + rs[1] + rs[2] + rs[3];
    sq  = rq[0] + rq[1] + rq[2] + rq[3];
    const float mean = sum * (1.0f / 512.0f);
    const float var  = (sq - 512.0f * mean * mean) * (1.0f / 511.0f);
    const float rstd = rsqrtf(var + 1e-5f);
    const float gg = g1[s], bb = b1[s];
#pragma unroll
    for (int k = 0; k < 2; ++k) {
        const int d = t + k * 256;
        n1[(size_t)row * 512 + d] = __float2bfloat16(gg * ((a[k] - mean) * rstd) + bb);
    }
}

// ---------------------------------------------------------------------------
// GEMM: out[r][n] = sum_d A[r][d] * W[n][d]   (A bf16 16384x512, W f32 512x512)
// BM=128 BN=64 BK=64, 4 waves (2x2), each wave 64x32 = 4x2 16x16 frags.
// MODE 0: += ts_emb[te[b]][n], write bf16 row-major
// MODE 1: write bf16 to (B,H,S,DH)     (Q or K)
// MODE 2: write bf16 to (B,H,DH,S)     (V transposed)
// MODE 3: += bo[n], write f32 row-major
// ---------------------------------------------------------------------------
template<int MODE>
__global__ __launch_bounds__(256) void gemm_k(
    const __hip_bfloat16* __restrict__ A,
    const float* __restrict__ W,
    void* __restrict__ outp,
    const float* __restrict__ aux,
    const int* __restrict__ te)
{
    __shared__ char lA[128 * 128];   // 128 rows x 64 bf16 (128B/row), swizzled
    __shared__ char lB[64 * 128];    // 64 rows x 64 bf16, swizzled

    const int t = threadIdx.x;
    const int lane = t & 63;
    const int wv = t >> 6;
    const int wm = wv & 1, wn = wv >> 1;
    const int Rb = blockIdx.x * 128;
    const int Nb = blockIdx.y * 64;
    const int g = lane >> 4, lr = lane & 15;

    const f32x4 zero = {0.f, 0.f, 0.f, 0.f};
    f32x4 acc[4][2];
#pragma unroll
    for (int i = 0; i < 4; ++i)
#pragma unroll
        for (int j = 0; j < 2; ++j) acc[i][j] = zero;

    for (int kt = 0; kt < 8; ++kt) {
        const int k0 = kt * 64;
        // stage A tile: 128x64 bf16
#pragma unroll
        for (int p = 0; p < 4; ++p) {
            const int idx = p * 256 + t;
            const int row = idx >> 3, ch = idx & 7;
            bf16x8 v = *reinterpret_cast<const bf16x8*>(
                A + (size_t)(Rb + row) * 512 + k0 + ch * 8);
            *reinterpret_cast<bf16x8*>(lA + row * 128 + ((ch ^ (row & 7)) << 4)) = v;
        }
        // stage W tile: 64x64 f32 -> bf16
        {
            const int row = t >> 2, seg = t & 3;
            const float4* wp = reinterpret_cast<const float4*>(
                W + (size_t)(Nb + row) * 512 + k0 + seg * 16);
            alignas(16) short tmp[16];
#pragma unroll
            for (int i = 0; i < 4; ++i) {
                const float4 f = wp[i];
                tmp[i * 4 + 0] = f2bf(f.x);
                tmp[i * 4 + 1] = f2bf(f.y);
                tmp[i * 4 + 2] = f2bf(f.z);
                tmp[i * 4 + 3] = f2bf(f.w);
            }
            const int c0 = seg * 2;
            *reinterpret_cast<bf16x8*>(lB + row * 128 + (((c0) ^ (row & 7)) << 4)) =
                *reinterpret_cast<bf16x8*>(tmp);
            *reinterpret_cast<bf16x8*>(lB + row * 128 + (((c0 + 1) ^ (row & 7)) << 4)) =
                *reinterpret_cast<bf16x8*>(tmp + 8);
        }
        __syncthreads();
#pragma unroll
        for (int kk = 0; kk < 2; ++kk) {
            bf16x8 af[4], bfv[2];
            const int ch = kk * 4 + g;
#pragma unroll
            for (int mt = 0; mt < 4; ++mt) {
                const int row = wm * 64 + mt * 16 + lr;
                af[mt] = *reinterpret_cast<const bf16x8*>(
                    lA + row * 128 + ((ch ^ (row & 7)) << 4));
            }
#pragma unroll
            for (int nt = 0; nt < 2; ++nt) {
                const int row = wn * 32 + nt * 16 + lr;
                bfv[nt] = *reinterpret_cast<const bf16x8*>(
                    lB + row * 128 + ((ch ^ (row & 7)) << 4));
            }
#pragma unroll
            for (int mt = 0; mt < 4; ++mt)
#pragma unroll
                for (int nt = 0; nt < 2; ++nt)
                    acc[mt][nt] = __builtin_amdgcn_mfma_f32_16x16x32_bf16(
                        af[mt], bfv[nt], acc[mt][nt], 0, 0, 0);
        }
        __syncthreads();
    }

    // epilogue
#pragma unroll
    for (int mt = 0; mt < 4; ++mt) {
#pragma unroll
        for (int nt = 0; nt < 2; ++nt) {
#pragma unroll
            for (int r = 0; r < 4; ++r) {
                const int R = Rb + wm * 64 + mt * 16 + 4 * g + r;
                const int N = Nb + wn * 32 + nt * 16 + lr;
                float v = acc[mt][nt][r];
                if (MODE == 0) {
                    const int b = R >> 10;
                    v += aux[(size_t)te[b] * 512 + N];
                    reinterpret_cast<__hip_bfloat16*>(outp)[(size_t)R * 512 + N] =
                        __float2bfloat16(v);
                } else if (MODE == 1) {
                    const int b = R >> 10, s = R & 1023, h = N >> 6, c = N & 63;
                    reinterpret_cast<__hip_bfloat16*>(outp)
                        [(((size_t)(b * 8 + h)) * 1024 + s) * 64 + c] = __float2bfloat16(v);
                } else if (MODE == 2) {
                    const int b = R >> 10, s = R & 1023, h = N >> 6, c = N & 63;
                    reinterpret_cast<__hip_bfloat16*>(outp)
                        [(((size_t)(b * 8 + h)) * 64 + c) * 1024 + s] = __float2bfloat16(v);
                } else {
                    reinterpret_cast<float*>(outp)[(size_t)R * 512 + N] = v + aux[N];
                }
            }
        }
    }
}

// ---------------------------------------------------------------------------
// Flash attention, transposed-score 32x32 form.
// out[j] = sum_{i<=j} softmax_i(Q_i.K_j) V_i.
// Scores via mfma(A=Q rows i, B=K rows j): lane holds 16 i's for j = lane&31
// -> softmax reduce is in-register + one shfl_xor(32).
// PV uses a PERMUTED-k MFMA: k-slot e of half l5 maps to
//   i_local = kt*16 + 4*l5 + (e<4 ? e : e+4)
// which is exactly the i-set each lane already holds in p[] (no cross-lane
// moves); V supplies rows in the same order via two 8B loads per fragment.
// Defer-max (T13, THR=8) skips o-rescale on most tiles.
// One (b,h) per blockIdx.y; 128 j per block, 4 waves x 32 j.
// ---------------------------------------------------------------------------
__global__ __launch_bounds__(256, 4) void attn2_k(
    const __hip_bfloat16* __restrict__ Qm,   // (B,H,S,64)
    const __hip_bfloat16* __restrict__ Km,   // (B,H,S,64)
    const __hip_bfloat16* __restrict__ Vt,   // (B,H,64,S)
    __hip_bfloat16* __restrict__ cat)        // (B,S,512)
{
    const int t = threadIdx.x, lane = t & 63, w = t >> 6;
    const int l5 = lane >> 5, ln31 = lane & 31;
    const int jb = 7 - blockIdx.x;           // big tiles first (tail packing)
    const int bh = blockIdx.y;
    const int b = bh >> 3, h = bh & 7;
    const int jw0 = jb * 128 + w * 32;

    const __hip_bfloat16* Qh = Qm + (size_t)bh * (S_ * 64);
    const __hip_bfloat16* Kh = Km + (size_t)bh * (S_ * 64);
    const __hip_bfloat16* Vh = Vt + (size_t)bh * (64 * S_);

    // hoisted B-operand: K rows jw0+ln31, 4 k-slices of DH=64
    bf16x8 kf[4];
#pragma unroll
    for (int kt = 0; kt < 4; ++kt)
        kf[kt] = *reinterpret_cast<const bf16x8*>(
            Kh + (size_t)(jw0 + ln31) * 64 + kt * 16 + l5 * 8);

    f32x16 o0, o1;
#pragma unroll
    for (int r = 0; r < 16; ++r) { o0[r] = 0.f; o1[r] = 0.f; }
    float m = -3e38f, lsum = 0.f;

    for (int i0 = 0; i0 <= jw0; i0 += 32) {
        // ---- QK^T: 32i x 32j, K=64 via 4 MFMAs -------------------------
        f32x16 sc;
#pragma unroll
        for (int r = 0; r < 16; ++r) sc[r] = 0.f;
#pragma unroll
        for (int kt = 0; kt < 4; ++kt) {
            bf16x8 qf = *reinterpret_cast<const bf16x8*>(
                Qh + (size_t)(i0 + ln31) * 64 + kt * 16 + l5 * 8);
            sc = __builtin_amdgcn_mfma_f32_32x32x16_bf16(qf, kf[kt], sc, 0, 0, 0);
        }
        // ---- scale + causal mask + per-j max (in-register) -------------
        const bool diag = (i0 == jw0);
        float p[16];
        float mx = -3e38f;
#pragma unroll
        for (int r = 0; r < 16; ++r) {
            const int irow = (r & 3) + 8 * (r >> 2) + 4 * l5;
            float v = sc[r] * 0.125f;
            if (diag && irow > ln31) v = -3e38f;
            p[r] = v;
            mx = fmaxf(mx, v);
        }
        mx = fmaxf(mx, __shfl_xor(mx, 32));
        // ---- defer-max rescale (T13) -----------------------------------
        if (!__all(mx <= m + 8.0f)) {
            const float mn = fmaxf(m, mx);
            const float alpha = __expf(m - mn);
            m = mn;
            lsum *= alpha;
#pragma unroll
            for (int r = 0; r < 16; ++r) {
                const int jrow = (r & 3) + 8 * (r >> 2) + 4 * l5;
                const float ar = __shfl(alpha, jrow);
                o0[r] *= ar; o1[r] *= ar;
            }
        }
        // ---- exp + per-j sum -------------------------------------------
        float ps = 0.f;
#pragma unroll
        for (int r = 0; r < 16; ++r) {
            p[r] = __expf(p[r] - m);
            ps += p[r];
        }
        ps += __shfl_xor(ps, 32);
        lsum += ps;
        // ---- P -> PV A-fragments (pure in-lane pack, permuted k) -------
        union { unsigned u[4]; bf16x8 v; } pa0, pa1;
        pa0.u[0] = pack_bf2(p[0],  p[1]);
        pa0.u[1] = pack_bf2(p[2],  p[3]);
        pa0.u[2] = pack_bf2(p[4],  p[5]);
        pa0.u[3] = pack_bf2(p[6],  p[7]);
        pa1.u[0] = pack_bf2(p[8],  p[9]);
        pa1.u[1] = pack_bf2(p[10], p[11]);
        pa1.u[2] = pack_bf2(p[12], p[13]);
        pa1.u[3] = pack_bf2(p[14], p[15]);
        // ---- PV: out[j][c] += P^T[j][i] V[i][c], 4 MFMAs ---------------
        // B-operand rows follow the same permuted-k order:
        //   e=0..3 -> i = base, e=4..7 -> i = base+8, base = i0+kt*16+4*l5
#pragma unroll
        for (int kt = 0; kt < 2; ++kt) {
            const bf16x8 pa = kt ? pa1.v : pa0.v;
            const int base = i0 + kt * 16 + 4 * l5;
            union { bf16x4 h[2]; bf16x8 v; } vf0, vf1;
            vf0.h[0] = *reinterpret_cast<const bf16x4*>(Vh + (size_t)ln31 * S_ + base);
            vf0.h[1] = *reinterpret_cast<const bf16x4*>(Vh + (size_t)ln31 * S_ + base + 8);
            vf1.h[0] = *reinterpret_cast<const bf16x4*>(Vh + (size_t)(32 + ln31) * S_ + base);
            vf1.h[1] = *reinterpret_cast<const bf16x4*>(Vh + (size_t)(32 + ln31) * S_ + base + 8);
            o0 = __builtin_amdgcn_mfma_f32_32x32x16_bf16(pa, vf0.v, o0, 0, 0, 0);
            o1 = __builtin_amdgcn_mfma_f32_32x32x16_bf16(pa, vf1.v, o1, 0, 0, 0);
        }
    }

    // ---- epilogue: divide by lsum (broadcast to row layout), store -----
    const float linv = 1.0f / lsum;
#pragma unroll
    for (int r = 0; r < 16; ++r) {
        const int jrow = (r & 3) + 8 * (r >> 2) + 4 * l5;
        const float rinv = __shfl(linv, jrow);
        const int j = jw0 + jrow;
        __hip_bfloat16* dst = cat + ((size_t)(b * 1024 + j)) * 512 + h * 64;
        dst[ln31]      = __float2bfloat16(o0[r] * rinv);
        dst[32 + ln31] = __float2bfloat16(o1[r] * rinv);
    }
}

// ---------------------------------------------------------------------------
// K5: residual (recompute conv) + LayerNorm over D, write (B,D,S) f32
// ---------------------------------------------------------------------------
__global__ __launch_bounds__(256) void k5_res_ln(
    const float* __restrict__ outf,  // (B*S,512) = Wo@cat + bo
    const float* __restrict__ ts, const float* __restrict__ conv_w,
    const float* __restrict__ conv_b, const float* __restrict__ pe,
    const float* __restrict__ g2, const float* __restrict__ b2,
    float* __restrict__ out)         // (B,512,1024)
{
    const int row = blockIdx.x;
    const int b = row >> 10, s = row & 1023;
    const int t = threadIdx.x;
    const float4 x = *reinterpret_cast<const float4*>(ts + b * 4096 + s * 4);

    float a[2];
#pragma unroll
    for (int k = 0; k < 2; ++k) {
        const int d = t + k * 256;
        const float4 w = *reinterpret_cast<const float4*>(conv_w + d * 4);
        const float conv = x.x * w.x + x.y * w.y + x.z * w.z + x.w * w.w
                         + conv_b[d] + pe[s * 512 + d];
        a[k] = outf[(size_t)row * 512 + d] + conv;
    }
    float sum = a[0] + a[1], sq = a[0] * a[0] + a[1] * a[1];
#pragma unroll
    for (int off = 32; off > 0; off >>= 1) {
        sum += __shfl_down(sum, off);
        sq  += __shfl_down(sq, off);
    }
    __shared__ float rs[4], rq[4];
    const int wv = t >> 6, ln = t & 63;
    if (ln == 0) { rs[wv] = sum; rq[wv] = sq; }
    __syncthreads();
    sum = rs[0] + rs[1] + rs[2] + rs[3];
    sq  = rq[0] + rq[1] + rq[2] + rq[3];
    const float mean = sum * (1.0f / 512.0f);
    const float var  = (sq - 512.0f * mean * mean) * (1.0f / 511.0f);
    const float rstd = rsqrtf(var + 1e-5f);
    const float gg = g2[s], bb = b2[s];
#pragma unroll
    for (int k = 0; k < 2; ++k) {
        const int d = t + k * 256;
        out[((size_t)b * 512 + d) * 1024 + s] = gg * ((a[k] - mean) * rstd) + bb;
    }
}

// ---------------------------------------------------------------------------
extern "C" void kernel_launch(void* const* d_in, const int* in_sizes, int n_in,
                              void* d_out, int out_size, void* d_ws, size_t ws_size,
                              hipStream_t stream)
{
    const float* ts     = (const float*)d_in[0];
    const int*   te     = (const int*)d_in[1];
    const float* conv_w = (const float*)d_in[2];
    const float* conv_b = (const float*)d_in[3];
    const float* pe     = (const float*)d_in[4];
    const float* ts_emb = (const float*)d_in[5];
    const float* g1     = (const float*)d_in[6];
    const float* b1     = (const float*)d_in[7];
    const float* M      = (const float*)d_in[8];
    const float* Wq     = (const float*)d_in[9];
    const float* Wk     = (const float*)d_in[10];
    const float* Wv     = (const float*)d_in[11];
    const float* Wo     = (const float*)d_in[12];
    const float* bo     = (const float*)d_in[13];
    const float* g2     = (const float*)d_in[14];
    const float* b2     = (const float*)d_in[15];

    char* ws = (char*)d_ws;
    __hip_bfloat16* n1    = (__hip_bfloat16*)(ws);                      // 16MB
    __hip_bfloat16* dense = (__hip_bfloat16*)(ws + (16ull << 20));      // 16MB
    __hip_bfloat16* q     = (__hip_bfloat16*)(ws + (32ull << 20));      // 16MB
    __hip_bfloat16* k     = (__hip_bfloat16*)(ws + (48ull << 20));      // 16MB
    __hip_bfloat16* vT    = (__hip_bfloat16*)(ws + (64ull << 20));      // 16MB
    __hip_bfloat16* cat   = (__hip_bfloat16*)(ws + (80ull << 20));      // 16MB
    float* outf           = (float*)(ws);  // reuse n1+dense region (32MB), both dead

    k1_conv_gelu_ln<<<16384, 256, 0, stream>>>(ts, conv_w, conv_b, pe, g1, b1, n1);
    gemm_k<0><<<dim3(128, 8), 256, 0, stream>>>(n1, M, dense, ts_emb, te);
    gemm_k<1><<<dim3(128, 8), 256, 0, stream>>>(dense, Wq, q, nullptr, nullptr);
    gemm_k<1><<<dim3(128, 8), 256, 0, stream>>>(dense, Wk, k, nullptr, nullptr);
    gemm_k<2><<<dim3(128, 8), 256, 0, stream>>>(dense, Wv, vT, nullptr, nullptr);
    attn2_k<<<dim3(8, 128), 256, 0, stream>>>(q, k, vT, cat);
    gemm_k<3><<<dim3(128, 8), 256, 0, stream>>>(cat, Wo, outf, bo, nullptr);
    k5_res_ln<<<16384, 256, 0, stream>>>(outf, ts, conv_w, conv_b, pe, g2, b2,
                                         (float*)d_out);
}

// Round 4
// 269.292 us; speedup vs baseline: 1.5045x; 1.2945x over previous
//
#include <hip/hip_runtime.h>
#include <hip/hip_bf16.h>

#define B_ 16
#define S_ 1024
#define D_ 512
#define H_ 8
#define DH_ 64

typedef __attribute__((ext_vector_type(8))) short bf16x8;
typedef __attribute__((ext_vector_type(4))) short bf16x4;
typedef __attribute__((ext_vector_type(4))) float f32x4;
typedef __attribute__((ext_vector_type(16))) float f32x16;

__device__ __forceinline__ short f2bf(float f) {
    __hip_bfloat16 h = __float2bfloat16(f);
    return *reinterpret_cast<short*>(&h);
}
__device__ __forceinline__ unsigned pack_bf2(float lo, float hi) {
    unsigned a = (unsigned)(unsigned short)f2bf(lo);
    unsigned b = (unsigned)(unsigned short)f2bf(hi);
    return a | (b << 16);
}

// ---------------------------------------------------------------------------
// K1: conv1d(stride=pool) + bias + pos-emb + exact GELU + LayerNorm over D
//     -> n1 bf16, layout (B*S, 512) row-major
// ---------------------------------------------------------------------------
__global__ __launch_bounds__(256) void k1_conv_gelu_ln(
    const float* __restrict__ ts, const float* __restrict__ conv_w,
    const float* __restrict__ conv_b, const float* __restrict__ pe,
    const float* __restrict__ g1, const float* __restrict__ b1,
    __hip_bfloat16* __restrict__ n1)
{
    const int row = blockIdx.x;          // b*S + s
    const int b = row >> 10, s = row & 1023;
    const int t = threadIdx.x;
    const float4 x = *reinterpret_cast<const float4*>(ts + b * 4096 + s * 4);

    float a[2];
#pragma unroll
    for (int k = 0; k < 2; ++k) {
        const int d = t + k * 256;
        const float4 w = *reinterpret_cast<const float4*>(conv_w + d * 4);
        float v = x.x * w.x + x.y * w.y + x.z * w.z + x.w * w.w
                + conv_b[d] + pe[s * 512 + d];
        a[k] = 0.5f * v * (1.0f + erff(v * 0.70710678118654752f));
    }
    float sum = a[0] + a[1], sq = a[0] * a[0] + a[1] * a[1];
#pragma unroll
    for (int off = 32; off > 0; off >>= 1) {
        sum += __shfl_down(sum, off);
        sq  += __shfl_down(sq, off);
    }
    __shared__ float rs[4], rq[4];
    const int wv = t >> 6, ln = t & 63;
    if (ln == 0) { rs[wv] = sum; rq[wv] = sq; }
    __syncthreads();
    sum = rs[0] + rs[1] + rs[2] + rs[3];
    sq  = rq[0] + rq[1] + rq[2] + rq[3];
    const float mean = sum * (1.0f / 512.0f);
    const float var  = (sq - 512.0f * mean * mean) * (1.0f / 511.0f);
    const float rstd = rsqrtf(var + 1e-5f);
    const float gg = g1[s], bb = b1[s];
#pragma unroll
    for (int k = 0; k < 2; ++k) {
        const int d = t + k * 256;
        n1[(size_t)row * 512 + d] = __float2bfloat16(gg * ((a[k] - mean) * rstd) + bb);
    }
}

// ---------------------------------------------------------------------------
// GEMM: out[r][n] = sum_d A[r][d] * W[n][d]   (A bf16 16384x512, W f32 512x512)
// BM=128 BN=64 BK=64, 4 waves (2x2), each wave 64x32 = 4x2 16x16 frags.
// MODE 0: += ts_emb[te[b]][n], write bf16 row-major
// MODE 1: write bf16 to (B,H,S,DH)     (K)
// MODE 2: write bf16 to (B,H,DH,S)     (V transposed)
// MODE 3: += bo[n], write f32 row-major
// MODE 4: MODE 1 layout, scaled by 0.125*log2(e)   (Q, softmax scale folded)
// ---------------------------------------------------------------------------
template<int MODE>
__global__ __launch_bounds__(256) void gemm_k(
    const __hip_bfloat16* __restrict__ A,
    const float* __restrict__ W,
    void* __restrict__ outp,
    const float* __restrict__ aux,
    const int* __restrict__ te)
{
    __shared__ char lA[128 * 128];   // 128 rows x 64 bf16 (128B/row), swizzled
    __shared__ char lB[64 * 128];    // 64 rows x 64 bf16, swizzled

    const int t = threadIdx.x;
    const int lane = t & 63;
    const int wv = t >> 6;
    const int wm = wv & 1, wn = wv >> 1;
    const int Rb = blockIdx.x * 128;
    const int Nb = blockIdx.y * 64;
    const int g = lane >> 4, lr = lane & 15;

    const f32x4 zero = {0.f, 0.f, 0.f, 0.f};
    f32x4 acc[4][2];
#pragma unroll
    for (int i = 0; i < 4; ++i)
#pragma unroll
        for (int j = 0; j < 2; ++j) acc[i][j] = zero;

    for (int kt = 0; kt < 8; ++kt) {
        const int k0 = kt * 64;
        // stage A tile: 128x64 bf16
#pragma unroll
        for (int p = 0; p < 4; ++p) {
            const int idx = p * 256 + t;
            const int row = idx >> 3, ch = idx & 7;
            bf16x8 v = *reinterpret_cast<const bf16x8*>(
                A + (size_t)(Rb + row) * 512 + k0 + ch * 8);
            *reinterpret_cast<bf16x8*>(lA + row * 128 + ((ch ^ (row & 7)) << 4)) = v;
        }
        // stage W tile: 64x64 f32 -> bf16
        {
            const int row = t >> 2, seg = t & 3;
            const float4* wp = reinterpret_cast<const float4*>(
                W + (size_t)(Nb + row) * 512 + k0 + seg * 16);
            alignas(16) short tmp[16];
#pragma unroll
            for (int i = 0; i < 4; ++i) {
                const float4 f = wp[i];
                tmp[i * 4 + 0] = f2bf(f.x);
                tmp[i * 4 + 1] = f2bf(f.y);
                tmp[i * 4 + 2] = f2bf(f.z);
                tmp[i * 4 + 3] = f2bf(f.w);
            }
            const int c0 = seg * 2;
            *reinterpret_cast<bf16x8*>(lB + row * 128 + (((c0) ^ (row & 7)) << 4)) =
                *reinterpret_cast<bf16x8*>(tmp);
            *reinterpret_cast<bf16x8*>(lB + row * 128 + (((c0 + 1) ^ (row & 7)) << 4)) =
                *reinterpret_cast<bf16x8*>(tmp + 8);
        }
        __syncthreads();
#pragma unroll
        for (int kk = 0; kk < 2; ++kk) {
            bf16x8 af[4], bfv[2];
            const int ch = kk * 4 + g;
#pragma unroll
            for (int mt = 0; mt < 4; ++mt) {
                const int row = wm * 64 + mt * 16 + lr;
                af[mt] = *reinterpret_cast<const bf16x8*>(
                    lA + row * 128 + ((ch ^ (row & 7)) << 4));
            }
#pragma unroll
            for (int nt = 0; nt < 2; ++nt) {
                const int row = wn * 32 + nt * 16 + lr;
                bfv[nt] = *reinterpret_cast<const bf16x8*>(
                    lB + row * 128 + ((ch ^ (row & 7)) << 4));
            }
#pragma unroll
            for (int mt = 0; mt < 4; ++mt)
#pragma unroll
                for (int nt = 0; nt < 2; ++nt)
                    acc[mt][nt] = __builtin_amdgcn_mfma_f32_16x16x32_bf16(
                        af[mt], bfv[nt], acc[mt][nt], 0, 0, 0);
        }
        __syncthreads();
    }

    // epilogue
#pragma unroll
    for (int mt = 0; mt < 4; ++mt) {
#pragma unroll
        for (int nt = 0; nt < 2; ++nt) {
#pragma unroll
            for (int r = 0; r < 4; ++r) {
                const int R = Rb + wm * 64 + mt * 16 + 4 * g + r;
                const int N = Nb + wn * 32 + nt * 16 + lr;
                float v = acc[mt][nt][r];
                if (MODE == 0) {
                    const int b = R >> 10;
                    v += aux[(size_t)te[b] * 512 + N];
                    reinterpret_cast<__hip_bfloat16*>(outp)[(size_t)R * 512 + N] =
                        __float2bfloat16(v);
                } else if (MODE == 1) {
                    const int b = R >> 10, s = R & 1023, h = N >> 6, c = N & 63;
                    reinterpret_cast<__hip_bfloat16*>(outp)
                        [(((size_t)(b * 8 + h)) * 1024 + s) * 64 + c] = __float2bfloat16(v);
                } else if (MODE == 2) {
                    const int b = R >> 10, s = R & 1023, h = N >> 6, c = N & 63;
                    reinterpret_cast<__hip_bfloat16*>(outp)
                        [(((size_t)(b * 8 + h)) * 64 + c) * 1024 + s] = __float2bfloat16(v);
                } else if (MODE == 4) {
                    const int b = R >> 10, s = R & 1023, h = N >> 6, c = N & 63;
                    reinterpret_cast<__hip_bfloat16*>(outp)
                        [(((size_t)(b * 8 + h)) * 1024 + s) * 64 + c] =
                        __float2bfloat16(v * 0.18033688011112042f); // 0.125*log2(e)
                } else {
                    reinterpret_cast<float*>(outp)[(size_t)R * 512 + N] = v + aux[N];
                }
            }
        }
    }
}

// ---------------------------------------------------------------------------
// Flash attention, transposed-score 32x32, dual balanced strips per wave.
// out[j] = sum_{i<=j} softmax_i(Q'_i.K_j) V_i, with Q' pre-scaled so the
// softmax runs in exp2 domain.
// Each wave owns strips sA = bx*4+w (0..15) and sB = 31-sA: uniform 33
// tile-steps per wave; during the dual phase both chains share the same
// Q/V tile loads (one load set feeds 16 MFMAs).
// PV uses the verified permuted-k mapping (in-lane P pack, split V loads).
// ---------------------------------------------------------------------------
__device__ __forceinline__ void attn_step(
    const bf16x8 (&qf)[4], const bf16x8 (&kf)[4],
    const bf16x8& v00, const bf16x8& v01,
    const bf16x8& v10, const bf16x8& v11,
    const bool diag, const int l5, const int ln31,
    float& m, float& lsum, f32x16& o0, f32x16& o1)
{
    f32x16 sc;
#pragma unroll
    for (int r = 0; r < 16; ++r) sc[r] = 0.f;
#pragma unroll
    for (int kt = 0; kt < 4; ++kt)
        sc = __builtin_amdgcn_mfma_f32_32x32x16_bf16(qf[kt], kf[kt], sc, 0, 0, 0);

    float p[16];
    float mx = -3e38f;
    if (diag) {
#pragma unroll
        for (int r = 0; r < 16; ++r) {
            const int irow = (r & 3) + 8 * (r >> 2) + 4 * l5;
            const float v = (irow > ln31) ? -3e38f : sc[r];
            p[r] = v; mx = fmaxf(mx, v);
        }
    } else {
#pragma unroll
        for (int r = 0; r < 16; ++r) { p[r] = sc[r]; mx = fmaxf(mx, sc[r]); }
    }
    mx = fmaxf(mx, __shfl_xor(mx, 32));
    if (!__all(mx <= m + 8.0f)) {          // defer-max (T13), log2 domain
        const float mn = fmaxf(m, mx);
        const float alpha = exp2f(m - mn);
        m = mn; lsum *= alpha;
#pragma unroll
        for (int r = 0; r < 16; ++r) {
            const int jrow = (r & 3) + 8 * (r >> 2) + 4 * l5;
            const float ar = __shfl(alpha, jrow);
            o0[r] *= ar; o1[r] *= ar;
        }
    }
    float ps = 0.f;
#pragma unroll
    for (int r = 0; r < 16; ++r) { p[r] = exp2f(p[r] - m); ps += p[r]; }
    ps += __shfl_xor(ps, 32);
    lsum += ps;

    union { unsigned u[4]; bf16x8 v; } pa0, pa1;
    pa0.u[0] = pack_bf2(p[0],  p[1]);  pa0.u[1] = pack_bf2(p[2],  p[3]);
    pa0.u[2] = pack_bf2(p[4],  p[5]);  pa0.u[3] = pack_bf2(p[6],  p[7]);
    pa1.u[0] = pack_bf2(p[8],  p[9]);  pa1.u[1] = pack_bf2(p[10], p[11]);
    pa1.u[2] = pack_bf2(p[12], p[13]); pa1.u[3] = pack_bf2(p[14], p[15]);
    o0 = __builtin_amdgcn_mfma_f32_32x32x16_bf16(pa0.v, v00, o0, 0, 0, 0);
    o0 = __builtin_amdgcn_mfma_f32_32x32x16_bf16(pa1.v, v01, o0, 0, 0, 0);
    o1 = __builtin_amdgcn_mfma_f32_32x32x16_bf16(pa0.v, v10, o1, 0, 0, 0);
    o1 = __builtin_amdgcn_mfma_f32_32x32x16_bf16(pa1.v, v11, o1, 0, 0, 0);
}

__device__ __forceinline__ void write_strip(
    __hip_bfloat16* __restrict__ dstbase, const int jw0,
    const f32x16& o0, const f32x16& o1, const float lsum,
    const int l5, const int ln31)
{
    const float linv = 1.0f / lsum;
#pragma unroll
    for (int r = 0; r < 16; ++r) {
        const int jrow = (r & 3) + 8 * (r >> 2) + 4 * l5;
        const float rinv = __shfl(linv, jrow);
        __hip_bfloat16* dst = dstbase + (size_t)(jw0 + jrow) * 512;
        dst[ln31]      = __float2bfloat16(o0[r] * rinv);
        dst[32 + ln31] = __float2bfloat16(o1[r] * rinv);
    }
}

__global__ __launch_bounds__(256, 2) void attn3_k(
    const __hip_bfloat16* __restrict__ Qm,   // (B,H,S,64), pre-scaled
    const __hip_bfloat16* __restrict__ Km,   // (B,H,S,64)
    const __hip_bfloat16* __restrict__ Vt,   // (B,H,64,S)
    __hip_bfloat16* __restrict__ cat)        // (B,S,512)
{
    const int t = threadIdx.x, lane = t & 63, w = t >> 6;
    const int l5 = lane >> 5, ln31 = lane & 31;
    const int bh = blockIdx.y;
    const int b = bh >> 3, h = bh & 7;
    const int sA = blockIdx.x * 4 + w;       // 0..15
    const int sB = 31 - sA;                  // 16..31
    const int jA = sA * 32, jB = sB * 32;
    const int nA = sA + 1, nB = sB + 1;

    const __hip_bfloat16* Qh = Qm + (size_t)bh * (S_ * 64);
    const __hip_bfloat16* Kh = Km + (size_t)bh * (S_ * 64);
    const __hip_bfloat16* Vh = Vt + (size_t)bh * (64 * S_);

    bf16x8 kfA[4], kfB[4];
#pragma unroll
    for (int kt = 0; kt < 4; ++kt) {
        kfA[kt] = *reinterpret_cast<const bf16x8*>(
            Kh + (size_t)(jA + ln31) * 64 + kt * 16 + l5 * 8);
        kfB[kt] = *reinterpret_cast<const bf16x8*>(
            Kh + (size_t)(jB + ln31) * 64 + kt * 16 + l5 * 8);
    }

    f32x16 oA0, oA1, oB0, oB1;
#pragma unroll
    for (int r = 0; r < 16; ++r) { oA0[r] = 0.f; oA1[r] = 0.f; oB0[r] = 0.f; oB1[r] = 0.f; }
    float mA = -3e38f, lA = 0.f, mB = -3e38f, lB = 0.f;

    const __hip_bfloat16* Vr0 = Vh + (size_t)ln31 * S_;
    const __hip_bfloat16* Vr1 = Vh + (size_t)(32 + ln31) * S_;

    for (int it = 0; it < nB; ++it) {
        const int i0 = it * 32;
        // shared tile loads (feed both chains)
        bf16x8 qf[4];
#pragma unroll
        for (int kt = 0; kt < 4; ++kt)
            qf[kt] = *reinterpret_cast<const bf16x8*>(
                Qh + (size_t)(i0 + ln31) * 64 + kt * 16 + l5 * 8);
        const int base0 = i0 + 4 * l5;
        const int base1 = i0 + 16 + 4 * l5;
        union u8 { bf16x4 h[2]; bf16x8 v; };
        u8 v00, v01, v10, v11;
        v00.h[0] = *reinterpret_cast<const bf16x4*>(Vr0 + base0);
        v00.h[1] = *reinterpret_cast<const bf16x4*>(Vr0 + base0 + 8);
        v01.h[0] = *reinterpret_cast<const bf16x4*>(Vr0 + base1);
        v01.h[1] = *reinterpret_cast<const bf16x4*>(Vr0 + base1 + 8);
        v10.h[0] = *reinterpret_cast<const bf16x4*>(Vr1 + base0);
        v10.h[1] = *reinterpret_cast<const bf16x4*>(Vr1 + base0 + 8);
        v11.h[0] = *reinterpret_cast<const bf16x4*>(Vr1 + base1);
        v11.h[1] = *reinterpret_cast<const bf16x4*>(Vr1 + base1 + 8);

        attn_step(qf, kfB, v00.v, v01.v, v10.v, v11.v,
                  it == nB - 1, l5, ln31, mB, lB, oB0, oB1);
        if (it < nA)
            attn_step(qf, kfA, v00.v, v01.v, v10.v, v11.v,
                      it == nA - 1, l5, ln31, mA, lA, oA0, oA1);
    }

    __hip_bfloat16* dstbase = cat + (size_t)b * 1024 * 512 + h * 64;
    write_strip(dstbase, jA, oA0, oA1, lA, l5, ln31);
    write_strip(dstbase, jB, oB0, oB1, lB, l5, ln31);
}

// ---------------------------------------------------------------------------
// K5: residual (recompute conv) + LayerNorm over D, write (B,D,S) f32
// ---------------------------------------------------------------------------
__global__ __launch_bounds__(256) void k5_res_ln(
    const float* __restrict__ outf,  // (B*S,512) = Wo@cat + bo
    const float* __restrict__ ts, const float* __restrict__ conv_w,
    const float* __restrict__ conv_b, const float* __restrict__ pe,
    const float* __restrict__ g2, const float* __restrict__ b2,
    float* __restrict__ out)         // (B,512,1024)
{
    const int row = blockIdx.x;
    const int b = row >> 10, s = row & 1023;
    const int t = threadIdx.x;
    const float4 x = *reinterpret_cast<const float4*>(ts + b * 4096 + s * 4);

    float a[2];
#pragma unroll
    for (int k = 0; k < 2; ++k) {
        const int d = t + k * 256;
        const float4 w = *reinterpret_cast<const float4*>(conv_w + d * 4);
        const float conv = x.x * w.x + x.y * w.y + x.z * w.z + x.w * w.w
                         + conv_b[d] + pe[s * 512 + d];
        a[k] = outf[(size_t)row * 512 + d] + conv;
    }
    float sum = a[0] + a[1], sq = a[0] * a[0] + a[1] * a[1];
#pragma unroll
    for (int off = 32; off > 0; off >>= 1) {
        sum += __shfl_down(sum, off);
        sq  += __shfl_down(sq, off);
    }
    __shared__ float rs[4], rq[4];
    const int wv = t >> 6, ln = t & 63;
    if (ln == 0) { rs[wv] = sum; rq[wv] = sq; }
    __syncthreads();
    sum = rs[0] + rs[1] + rs[2] + rs[3];
    sq  = rq[0] + rq[1] + rq[2] + rq[3];
    const float mean = sum * (1.0f / 512.0f);
    const float var  = (sq - 512.0f * mean * mean) * (1.0f / 511.0f);
    const float rstd = rsqrtf(var + 1e-5f);
    const float gg = g2[s], bb = b2[s];
#pragma unroll
    for (int k = 0; k < 2; ++k) {
        const int d = t + k * 256;
        out[((size_t)b * 512 + d) * 1024 + s] = gg * ((a[k] - mean) * rstd) + bb;
    }
}

// ---------------------------------------------------------------------------
extern "C" void kernel_launch(void* const* d_in, const int* in_sizes, int n_in,
                              void* d_out, int out_size, void* d_ws, size_t ws_size,
                              hipStream_t stream)
{
    const float* ts     = (const float*)d_in[0];
    const int*   te     = (const int*)d_in[1];
    const float* conv_w = (const float*)d_in[2];
    const float* conv_b = (const float*)d_in[3];
    const float* pe     = (const float*)d_in[4];
    const float* ts_emb = (const float*)d_in[5];
    const float* g1     = (const float*)d_in[6];
    const float* b1     = (const float*)d_in[7];
    const float* M      = (const float*)d_in[8];
    const float* Wq     = (const float*)d_in[9];
    const float* Wk     = (const float*)d_in[10];
    const float* Wv     = (const float*)d_in[11];
    const float* Wo     = (const float*)d_in[12];
    const float* bo     = (const float*)d_in[13];
    const float* g2     = (const float*)d_in[14];
    const float* b2     = (const float*)d_in[15];

    char* ws = (char*)d_ws;
    __hip_bfloat16* n1    = (__hip_bfloat16*)(ws);                      // 16MB
    __hip_bfloat16* dense = (__hip_bfloat16*)(ws + (16ull << 20));      // 16MB
    __hip_bfloat16* q     = (__hip_bfloat16*)(ws + (32ull << 20));      // 16MB
    __hip_bfloat16* k     = (__hip_bfloat16*)(ws + (48ull << 20));      // 16MB
    __hip_bfloat16* vT    = (__hip_bfloat16*)(ws + (64ull << 20));      // 16MB
    __hip_bfloat16* cat   = (__hip_bfloat16*)(ws + (80ull << 20));      // 16MB
    float* outf           = (float*)(ws);  // reuse n1+dense region (32MB), both dead

    k1_conv_gelu_ln<<<16384, 256, 0, stream>>>(ts, conv_w, conv_b, pe, g1, b1, n1);
    gemm_k<0><<<dim3(128, 8), 256, 0, stream>>>(n1, M, dense, ts_emb, te);
    gemm_k<4><<<dim3(128, 8), 256, 0, stream>>>(dense, Wq, q, nullptr, nullptr);
    gemm_k<1><<<dim3(128, 8), 256, 0, stream>>>(dense, Wk, k, nullptr, nullptr);
    gemm_k<2><<<dim3(128, 8), 256, 0, stream>>>(dense, Wv, vT, nullptr, nullptr);
    attn3_k<<<dim3(4, 128), 256, 0, stream>>>(q, k, vT, cat);
    gemm_k<3><<<dim3(128, 8), 256, 0, stream>>>(cat, Wo, outf, bo, nullptr);
    k5_res_ln<<<16384, 256, 0, stream>>>(outf, ts, conv_w, conv_b, pe, g2, b2,
                                         (float*)d_out);
}

// Round 5
// 210.699 us; speedup vs baseline: 1.9229x; 1.2781x over previous
//
#include <hip/hip_runtime.h>
#include <hip/hip_bf16.h>

#define B_ 16
#define S_ 1024
#define D_ 512
#define H_ 8
#define DH_ 64

typedef __attribute__((ext_vector_type(8))) short bf16x8;
typedef __attribute__((ext_vector_type(4))) short bf16x4;
typedef __attribute__((ext_vector_type(4))) float f32x4;
typedef __attribute__((ext_vector_type(16))) float f32x16;

__device__ __forceinline__ short f2bf(float f) {
    __hip_bfloat16 h = __float2bfloat16(f);
    return *reinterpret_cast<short*>(&h);
}
__device__ __forceinline__ unsigned pack_bf2(float lo, float hi) {
    unsigned a = (unsigned)(unsigned short)f2bf(lo);
    unsigned b = (unsigned)(unsigned short)f2bf(hi);
    return a | (b << 16);
}
__device__ __forceinline__ void gload16(const void* g, void* l) {
    __builtin_amdgcn_global_load_lds(
        (const __attribute__((address_space(1))) unsigned int*)g,
        (__attribute__((address_space(3))) unsigned int*)l, 16, 0, 0);
}

// ---------------------------------------------------------------------------
// prep_w: convert the 5 weight matrices (512x512 f32 each) to bf16 in ws.
// Order: M, Wq (pre-scaled by 0.125*log2e), Wk, Wv, Wo. 8 elems/thread.
// ---------------------------------------------------------------------------
__global__ __launch_bounds__(256) void prep_w(
    const float* __restrict__ M, const float* __restrict__ Wq,
    const float* __restrict__ Wk, const float* __restrict__ Wv,
    const float* __restrict__ Wo, __hip_bfloat16* __restrict__ wb)
{
    const int gid = blockIdx.x * 256 + threadIdx.x;
    const int e8 = gid * 8;
    const int w = e8 >> 18;              // 262144 elems per weight
    const int off = e8 & 262143;
    const float* src = (w == 0) ? M : (w == 1) ? Wq : (w == 2) ? Wk
                      : (w == 3) ? Wv : Wo;
    const float scale = (w == 1) ? 0.18033688011112042f : 1.0f;
    const float4 f0 = *reinterpret_cast<const float4*>(src + off);
    const float4 f1 = *reinterpret_cast<const float4*>(src + off + 4);
    union { short s[8]; bf16x8 v; } r;
    r.s[0] = f2bf(f0.x * scale); r.s[1] = f2bf(f0.y * scale);
    r.s[2] = f2bf(f0.z * scale); r.s[3] = f2bf(f0.w * scale);
    r.s[4] = f2bf(f1.x * scale); r.s[5] = f2bf(f1.y * scale);
    r.s[6] = f2bf(f1.z * scale); r.s[7] = f2bf(f1.w * scale);
    *reinterpret_cast<bf16x8*>(wb + e8) = r.v;
}

// ---------------------------------------------------------------------------
// K1: conv1d(stride=pool) + bias + pos-emb + exact GELU + LayerNorm over D
//     -> n1 bf16, layout (B*S, 512) row-major
// ---------------------------------------------------------------------------
__global__ __launch_bounds__(256) void k1_conv_gelu_ln(
    const float* __restrict__ ts, const float* __restrict__ conv_w,
    const float* __restrict__ conv_b, const float* __restrict__ pe,
    const float* __restrict__ g1, const float* __restrict__ b1,
    __hip_bfloat16* __restrict__ n1)
{
    const int row = blockIdx.x;          // b*S + s
    const int b = row >> 10, s = row & 1023;
    const int t = threadIdx.x;
    const float4 x = *reinterpret_cast<const float4*>(ts + b * 4096 + s * 4);

    float a[2];
#pragma unroll
    for (int k = 0; k < 2; ++k) {
        const int d = t + k * 256;
        const float4 w = *reinterpret_cast<const float4*>(conv_w + d * 4);
        float v = x.x * w.x + x.y * w.y + x.z * w.z + x.w * w.w
                + conv_b[d] + pe[s * 512 + d];
        a[k] = 0.5f * v * (1.0f + erff(v * 0.70710678118654752f));
    }
    float sum = a[0] + a[1], sq = a[0] * a[0] + a[1] * a[1];
#pragma unroll
    for (int off = 32; off > 0; off >>= 1) {
        sum += __shfl_down(sum, off);
        sq  += __shfl_down(sq, off);
    }
    __shared__ float rs[4], rq[4];
    const int wv = t >> 6, ln = t & 63;
    if (ln == 0) { rs[wv] = sum; rq[wv] = sq; }
    __syncthreads();
    sum = rs[0] + rs[1] + rs[2] + rs[3];
    sq  = rq[0] + rq[1] + rq[2] + rq[3];
    const float mean = sum * (1.0f / 512.0f);
    const float var  = (sq - 512.0f * mean * mean) * (1.0f / 511.0f);
    const float rstd = rsqrtf(var + 1e-5f);
    const float gg = g1[s], bb = b1[s];
#pragma unroll
    for (int k = 0; k < 2; ++k) {
        const int d = t + k * 256;
        n1[(size_t)row * 512 + d] = __float2bfloat16(gg * ((a[k] - mean) * rstd) + bb);
    }
}

// ---------------------------------------------------------------------------
// GEMM: out[r][n] = sum_d A[r][d] * Wb[n][d]  (A bf16 16384x512, Wb bf16 512x512)
// BM=128 BN=128 BK=64, 4 waves (2x2), each wave 64x64 = 4x4 16x16 frags.
// Staging via global_load_lds width=16 with pre-swizzled global source:
//   LDS slot s of row holds chunk s^(row&7); lane l -> row=l>>3, slot=l&7,
//   so global chunk fetched = (l&7)^(l>>3).
// MODE 0: += ts_emb[te[b]][n], write bf16 row-major (dense)
// MODE 1: write bf16 to (B,H,S,DH)   (Q [prescaled via Wq] and K)
// MODE 2: write bf16 to (B,H,DH,S)   (V transposed)
// MODE 3: += bo[n], write f32 row-major
// ---------------------------------------------------------------------------
template<int MODE>
__global__ __launch_bounds__(256) void gemm_k(
    const __hip_bfloat16* __restrict__ A,
    const __hip_bfloat16* __restrict__ Wb,
    void* __restrict__ outp,
    const float* __restrict__ aux,
    const int* __restrict__ te)
{
    __shared__ char lA[128 * 128];   // 128 rows x 64 bf16, 16B-chunk swizzled
    __shared__ char lB[128 * 128];

    const int t = threadIdx.x;
    const int lane = t & 63;
    const int w = t >> 6;
    const int wm = w & 1, wn = w >> 1;
    const int Rb = blockIdx.x * 128;
    const int Nb = blockIdx.y * 128;
    const int g = lane >> 4, lr = lane & 15;
    const int lrow = lane >> 3;              // 0..7
    const int coff = ((lane & 7) ^ lrow) * 8;  // pre-swizzled element offset

    f32x4 acc[4][4];
#pragma unroll
    for (int i = 0; i < 4; ++i)
#pragma unroll
        for (int j = 0; j < 4; ++j) acc[i][j] = {0.f, 0.f, 0.f, 0.f};

    for (int kt = 0; kt < 8; ++kt) {
        const int k0 = kt * 64;
#pragma unroll
        for (int i = 0; i < 4; ++i) {
            const int r0 = w * 32 + i * 8;
            gload16(A + (size_t)(Rb + r0 + lrow) * 512 + k0 + coff, lA + r0 * 128);
        }
#pragma unroll
        for (int i = 0; i < 4; ++i) {
            const int r0 = w * 32 + i * 8;
            gload16(Wb + (size_t)(Nb + r0 + lrow) * 512 + k0 + coff, lB + r0 * 128);
        }
        __syncthreads();
#pragma unroll
        for (int kk = 0; kk < 2; ++kk) {
            bf16x8 af[4], bfv[4];
            const int ch = kk * 4 + g;
#pragma unroll
            for (int mt = 0; mt < 4; ++mt) {
                const int row = wm * 64 + mt * 16 + lr;
                af[mt] = *reinterpret_cast<const bf16x8*>(
                    lA + row * 128 + ((ch ^ (row & 7)) << 4));
            }
#pragma unroll
            for (int nt = 0; nt < 4; ++nt) {
                const int row = wn * 64 + nt * 16 + lr;
                bfv[nt] = *reinterpret_cast<const bf16x8*>(
                    lB + row * 128 + ((ch ^ (row & 7)) << 4));
            }
#pragma unroll
            for (int mt = 0; mt < 4; ++mt)
#pragma unroll
                for (int nt = 0; nt < 4; ++nt)
                    acc[mt][nt] = __builtin_amdgcn_mfma_f32_16x16x32_bf16(
                        af[mt], bfv[nt], acc[mt][nt], 0, 0, 0);
        }
        __syncthreads();
    }

    // epilogue
#pragma unroll
    for (int mt = 0; mt < 4; ++mt) {
#pragma unroll
        for (int nt = 0; nt < 4; ++nt) {
#pragma unroll
            for (int r = 0; r < 4; ++r) {
                const int R = Rb + wm * 64 + mt * 16 + 4 * g + r;
                const int N = Nb + wn * 64 + nt * 16 + lr;
                float v = acc[mt][nt][r];
                if (MODE == 0) {
                    const int b = R >> 10;
                    v += aux[(size_t)te[b] * 512 + N];
                    reinterpret_cast<__hip_bfloat16*>(outp)[(size_t)R * 512 + N] =
                        __float2bfloat16(v);
                } else if (MODE == 1) {
                    const int b = R >> 10, s = R & 1023, h = N >> 6, c = N & 63;
                    reinterpret_cast<__hip_bfloat16*>(outp)
                        [(((size_t)(b * 8 + h)) * 1024 + s) * 64 + c] = __float2bfloat16(v);
                } else if (MODE == 2) {
                    const int b = R >> 10, s = R & 1023, h = N >> 6, c = N & 63;
                    reinterpret_cast<__hip_bfloat16*>(outp)
                        [(((size_t)(b * 8 + h)) * 64 + c) * 1024 + s] = __float2bfloat16(v);
                } else {
                    reinterpret_cast<float*>(outp)[(size_t)R * 512 + N] = v + aux[N];
                }
            }
        }
    }
}

// ---------------------------------------------------------------------------
// Flash attention, transposed-score 32x32, dual balanced strips per wave,
// register-prefetched tiles (next Q/V loads overlap current step's compute).
// Q pre-scaled by 0.125*log2e (folded into Wq) -> exp2 softmax domain.
// ---------------------------------------------------------------------------
__device__ __forceinline__ void attn_step(
    const bf16x8 (&qf)[4], const bf16x8 (&kf)[4],
    const bf16x8& v00, const bf16x8& v01,
    const bf16x8& v10, const bf16x8& v11,
    const bool diag, const int l5, const int ln31,
    float& m, float& lsum, f32x16& o0, f32x16& o1)
{
    f32x16 sc;
#pragma unroll
    for (int r = 0; r < 16; ++r) sc[r] = 0.f;
#pragma unroll
    for (int kt = 0; kt < 4; ++kt)
        sc = __builtin_amdgcn_mfma_f32_32x32x16_bf16(qf[kt], kf[kt], sc, 0, 0, 0);

    float p[16];
    float mx = -3e38f;
    if (diag) {
#pragma unroll
        for (int r = 0; r < 16; ++r) {
            const int irow = (r & 3) + 8 * (r >> 2) + 4 * l5;
            const float v = (irow > ln31) ? -3e38f : sc[r];
            p[r] = v; mx = fmaxf(mx, v);
        }
    } else {
#pragma unroll
        for (int r = 0; r < 16; ++r) { p[r] = sc[r]; mx = fmaxf(mx, sc[r]); }
    }
    mx = fmaxf(mx, __shfl_xor(mx, 32));
    if (!__all(mx <= m + 8.0f)) {          // defer-max (T13), log2 domain
        const float mn = fmaxf(m, mx);
        const float alpha = exp2f(m - mn);
        m = mn; lsum *= alpha;
#pragma unroll
        for (int r = 0; r < 16; ++r) {
            const int jrow = (r & 3) + 8 * (r >> 2) + 4 * l5;
            const float ar = __shfl(alpha, jrow);
            o0[r] *= ar; o1[r] *= ar;
        }
    }
    float ps = 0.f;
#pragma unroll
    for (int r = 0; r < 16; ++r) { p[r] = exp2f(p[r] - m); ps += p[r]; }
    ps += __shfl_xor(ps, 32);
    lsum += ps;

    union { unsigned u[4]; bf16x8 v; } pa0, pa1;
    pa0.u[0] = pack_bf2(p[0],  p[1]);  pa0.u[1] = pack_bf2(p[2],  p[3]);
    pa0.u[2] = pack_bf2(p[4],  p[5]);  pa0.u[3] = pack_bf2(p[6],  p[7]);
    pa1.u[0] = pack_bf2(p[8],  p[9]);  pa1.u[1] = pack_bf2(p[10], p[11]);
    pa1.u[2] = pack_bf2(p[12], p[13]); pa1.u[3] = pack_bf2(p[14], p[15]);
    o0 = __builtin_amdgcn_mfma_f32_32x32x16_bf16(pa0.v, v00, o0, 0, 0, 0);
    o0 = __builtin_amdgcn_mfma_f32_32x32x16_bf16(pa1.v, v01, o0, 0, 0, 0);
    o1 = __builtin_amdgcn_mfma_f32_32x32x16_bf16(pa0.v, v10, o1, 0, 0, 0);
    o1 = __builtin_amdgcn_mfma_f32_32x32x16_bf16(pa1.v, v11, o1, 0, 0, 0);
}

__device__ __forceinline__ void write_strip(
    __hip_bfloat16* __restrict__ dstbase, const int jw0,
    const f32x16& o0, const f32x16& o1, const float lsum,
    const int l5, const int ln31)
{
    const float linv = 1.0f / lsum;
#pragma unroll
    for (int r = 0; r < 16; ++r) {
        const int jrow = (r & 3) + 8 * (r >> 2) + 4 * l5;
        const float rinv = __shfl(linv, jrow);
        __hip_bfloat16* dst = dstbase + (size_t)(jw0 + jrow) * 512;
        dst[ln31]      = __float2bfloat16(o0[r] * rinv);
        dst[32 + ln31] = __float2bfloat16(o1[r] * rinv);
    }
}

__global__ __launch_bounds__(256, 2) void attn3_k(
    const __hip_bfloat16* __restrict__ Qm,   // (B,H,S,64), pre-scaled
    const __hip_bfloat16* __restrict__ Km,   // (B,H,S,64)
    const __hip_bfloat16* __restrict__ Vt,   // (B,H,64,S)
    __hip_bfloat16* __restrict__ cat)        // (B,S,512)
{
    const int t = threadIdx.x, lane = t & 63, w = t >> 6;
    const int l5 = lane >> 5, ln31 = lane & 31;
    const int bh = blockIdx.y;
    const int b = bh >> 3, h = bh & 7;
    const int sA = blockIdx.x * 4 + w;       // 0..15
    const int sB = 31 - sA;                  // 16..31
    const int jA = sA * 32, jB = sB * 32;
    const int nA = sA + 1, nB = sB + 1;

    const __hip_bfloat16* Qh = Qm + (size_t)bh * (S_ * 64);
    const __hip_bfloat16* Kh = Km + (size_t)bh * (S_ * 64);
    const __hip_bfloat16* Vh = Vt + (size_t)bh * (64 * S_);

    bf16x8 kfA[4], kfB[4];
#pragma unroll
    for (int kt = 0; kt < 4; ++kt) {
        kfA[kt] = *reinterpret_cast<const bf16x8*>(
            Kh + (size_t)(jA + ln31) * 64 + kt * 16 + l5 * 8);
        kfB[kt] = *reinterpret_cast<const bf16x8*>(
            Kh + (size_t)(jB + ln31) * 64 + kt * 16 + l5 * 8);
    }

    f32x16 oA0, oA1, oB0, oB1;
#pragma unroll
    for (int r = 0; r < 16; ++r) { oA0[r] = 0.f; oA1[r] = 0.f; oB0[r] = 0.f; oB1[r] = 0.f; }
    float mA = -3e38f, lsA = 0.f, mB = -3e38f, lsB = 0.f;

    const __hip_bfloat16* Vr0 = Vh + (size_t)ln31 * S_;
    const __hip_bfloat16* Vr1 = Vh + (size_t)(32 + ln31) * S_;

    union u8 { bf16x4 h[2]; bf16x8 v; };
    bf16x8 qf[4]; u8 v00, v01, v10, v11;

    auto load_q = [&](int i0, bf16x8 (&dst)[4]) {
#pragma unroll
        for (int kt = 0; kt < 4; ++kt)
            dst[kt] = *reinterpret_cast<const bf16x8*>(
                Qh + (size_t)(i0 + ln31) * 64 + kt * 16 + l5 * 8);
    };
    auto load_v = [&](int i0, u8& a0, u8& a1, u8& a2, u8& a3) {
        const int b0 = i0 + 4 * l5, b1 = i0 + 16 + 4 * l5;
        a0.h[0] = *reinterpret_cast<const bf16x4*>(Vr0 + b0);
        a0.h[1] = *reinterpret_cast<const bf16x4*>(Vr0 + b0 + 8);
        a1.h[0] = *reinterpret_cast<const bf16x4*>(Vr0 + b1);
        a1.h[1] = *reinterpret_cast<const bf16x4*>(Vr0 + b1 + 8);
        a2.h[0] = *reinterpret_cast<const bf16x4*>(Vr1 + b0);
        a2.h[1] = *reinterpret_cast<const bf16x4*>(Vr1 + b0 + 8);
        a3.h[0] = *reinterpret_cast<const bf16x4*>(Vr1 + b1);
        a3.h[1] = *reinterpret_cast<const bf16x4*>(Vr1 + b1 + 8);
    };

    load_q(0, qf);
    load_v(0, v00, v01, v10, v11);

    for (int it = 0; it < nB; ++it) {
        const int ipf = (it + 1 < nB ? it + 1 : it) * 32;   // clamp (safe re-load)
        bf16x8 qn[4]; u8 n00, n01, n10, n11;
        load_q(ipf, qn);
        load_v(ipf, n00, n01, n10, n11);

        attn_step(qf, kfB, v00.v, v01.v, v10.v, v11.v,
                  it == nB - 1, l5, ln31, mB, lsB, oB0, oB1);
        if (it < nA)
            attn_step(qf, kfA, v00.v, v01.v, v10.v, v11.v,
                      it == nA - 1, l5, ln31, mA, lsA, oA0, oA1);

#pragma unroll
        for (int kt = 0; kt < 4; ++kt) qf[kt] = qn[kt];
        v00 = n00; v01 = n01; v10 = n10; v11 = n11;
    }

    __hip_bfloat16* dstbase = cat + (size_t)b * 1024 * 512 + h * 64;
    write_strip(dstbase, jA, oA0, oA1, lsA, l5, ln31);
    write_strip(dstbase, jB, oB0, oB1, lsB, l5, ln31);
}

// ---------------------------------------------------------------------------
// K5: residual (recompute conv) + LayerNorm over D, transposed store.
// Block = (b, 16-s chunk). LDS transpose so (B,D,S) f32 writes are 64B runs.
// ---------------------------------------------------------------------------
__global__ __launch_bounds__(256) void k5_res_ln(
    const float* __restrict__ outf,  // (B*S,512) = Wo@cat + bo
    const float* __restrict__ ts, const float* __restrict__ conv_w,
    const float* __restrict__ conv_b, const float* __restrict__ pe,
    const float* __restrict__ g2, const float* __restrict__ b2,
    float* __restrict__ out)         // (B,512,1024)
{
    __shared__ float tile[16 * 520];     // [sl][d], pad 520 to break banks
    const int blk = blockIdx.x;          // b*64 + schunk
    const int b = blk >> 6, s0 = (blk & 63) * 16;
    const int t = threadIdx.x;
    const int sl = t >> 4, c = t & 15;
    const int s = s0 + sl;

    const float4 x = *reinterpret_cast<const float4*>(ts + b * 4096 + s * 4);
    float vals[32];
    float sum = 0.f, sq = 0.f;
#pragma unroll
    for (int j = 0; j < 32; ++j) {
        const int d = c + 16 * j;
        const float4 wv = *reinterpret_cast<const float4*>(conv_w + d * 4);
        const float conv = x.x * wv.x + x.y * wv.y + x.z * wv.z + x.w * wv.w
                         + conv_b[d] + pe[s * 512 + d];
        const float a = outf[(size_t)(b * 1024 + s) * 512 + d] + conv;
        vals[j] = a; sum += a; sq += a * a;
    }
#pragma unroll
    for (int off = 1; off < 16; off <<= 1) {
        sum += __shfl_xor(sum, off);
        sq  += __shfl_xor(sq, off);
    }
    const float mean = sum * (1.0f / 512.0f);
    const float var  = (sq - 512.0f * mean * mean) * (1.0f / 511.0f);
    const float rstd = rsqrtf(var + 1e-5f);
    const float gg = g2[s], bb = b2[s];
#pragma unroll
    for (int j = 0; j < 32; ++j) {
        const int d = c + 16 * j;
        tile[sl * 520 + d] = gg * ((vals[j] - mean) * rstd) + bb;
    }
    __syncthreads();
#pragma unroll
    for (int q2 = 0; q2 < 2; ++q2) {
        const int d = t + q2 * 256;
        float buf[16];
#pragma unroll
        for (int sl2 = 0; sl2 < 16; ++sl2) buf[sl2] = tile[sl2 * 520 + d];
        float4* dst = reinterpret_cast<float4*>(
            out + ((size_t)b * 512 + d) * 1024 + s0);
        dst[0] = make_float4(buf[0],  buf[1],  buf[2],  buf[3]);
        dst[1] = make_float4(buf[4],  buf[5],  buf[6],  buf[7]);
        dst[2] = make_float4(buf[8],  buf[9],  buf[10], buf[11]);
        dst[3] = make_float4(buf[12], buf[13], buf[14], buf[15]);
    }
}

// ---------------------------------------------------------------------------
extern "C" void kernel_launch(void* const* d_in, const int* in_sizes, int n_in,
                              void* d_out, int out_size, void* d_ws, size_t ws_size,
                              hipStream_t stream)
{
    const float* ts     = (const float*)d_in[0];
    const int*   te     = (const int*)d_in[1];
    const float* conv_w = (const float*)d_in[2];
    const float* conv_b = (const float*)d_in[3];
    const float* pe     = (const float*)d_in[4];
    const float* ts_emb = (const float*)d_in[5];
    const float* g1     = (const float*)d_in[6];
    const float* b1     = (const float*)d_in[7];
    const float* M      = (const float*)d_in[8];
    const float* Wq     = (const float*)d_in[9];
    const float* Wk     = (const float*)d_in[10];
    const float* Wv     = (const float*)d_in[11];
    const float* Wo     = (const float*)d_in[12];
    const float* bo     = (const float*)d_in[13];
    const float* g2     = (const float*)d_in[14];
    const float* b2     = (const float*)d_in[15];

    char* ws = (char*)d_ws;
    __hip_bfloat16* wb    = (__hip_bfloat16*)(ws);                 // 2.5MB @0
    __hip_bfloat16* Mb    = wb;
    __hip_bfloat16* Wqb   = wb + 262144;
    __hip_bfloat16* Wkb   = wb + 2 * 262144;
    __hip_bfloat16* Wvb   = wb + 3 * 262144;
    __hip_bfloat16* Wob   = wb + 4 * 262144;
    __hip_bfloat16* n1    = (__hip_bfloat16*)(ws + ( 3ull << 20)); // 16MB @3
    __hip_bfloat16* cat   = n1;                                    // reuse @3
    __hip_bfloat16* dense = (__hip_bfloat16*)(ws + (19ull << 20)); // 16MB @19
    float*          outf  = (float*)(ws + (19ull << 20));          // 32MB @19 (dense+q dead)
    __hip_bfloat16* q     = (__hip_bfloat16*)(ws + (35ull << 20)); // 16MB @35
    __hip_bfloat16* k     = (__hip_bfloat16*)(ws + (51ull << 20)); // 16MB @51
    __hip_bfloat16* vT    = (__hip_bfloat16*)(ws + (67ull << 20)); // 16MB @67

    prep_w<<<640, 256, 0, stream>>>(M, Wq, Wk, Wv, Wo, wb);
    k1_conv_gelu_ln<<<16384, 256, 0, stream>>>(ts, conv_w, conv_b, pe, g1, b1, n1);
    gemm_k<0><<<dim3(128, 4), 256, 0, stream>>>(n1, Mb, dense, ts_emb, te);
    gemm_k<1><<<dim3(128, 4), 256, 0, stream>>>(dense, Wqb, q, nullptr, nullptr);
    gemm_k<1><<<dim3(128, 4), 256, 0, stream>>>(dense, Wkb, k, nullptr, nullptr);
    gemm_k<2><<<dim3(128, 4), 256, 0, stream>>>(dense, Wvb, vT, nullptr, nullptr);
    attn3_k<<<dim3(4, 128), 256, 0, stream>>>(q, k, vT, cat);
    gemm_k<3><<<dim3(128, 4), 256, 0, stream>>>(cat, Wob, outf, bo, nullptr);
    k5_res_ln<<<1024, 256, 0, stream>>>(outf, ts, conv_w, conv_b, pe, g2, b2,
                                        (float*)d_out);
}